// Round 1
// 3399.756 us; speedup vs baseline: 2.0329x; 2.0329x over previous
//
#include <hip/hip_runtime.h>

#define T_TOK 1024
#define H_DIM 2048
#define E_NUM 32
#define F_DIM 1408
#define SF_DIM 5632
#define PAIRS 4096
#define MAXROWS 6144   // 4096 pairs + 32 experts * 63 pad, rounded
#define MAXT64 96      // max 64-row tiles: sum ceil(c_e/64) <= 4096/64 + 32 = 96
#define BK 16

__device__ __forceinline__ float silu_mul(float g, float u) {
    return g / (1.f + __expf(-g)) * u;
}

// ---------------- Router: logits, softmax, top-4, sigmoid shared gate ----------------
__global__ __launch_bounds__(256) void router_kernel(
    const float* __restrict__ x, const float* __restrict__ gw,
    const float* __restrict__ segw, float* __restrict__ logits_out,
    int* __restrict__ topk_idx, float* __restrict__ topk_w,
    float* __restrict__ seg_out, int* __restrict__ counts)
{
    __shared__ float xs[H_DIM];
    __shared__ float red[32][9];
    __shared__ float sred[256];
    __shared__ float logit[32];
    int t = blockIdx.x, tid = threadIdx.x;
    for (int i = tid; i < H_DIM; i += 256) xs[i] = x[(size_t)t * H_DIM + i];
    __syncthreads();
    int e = tid >> 3, c = tid & 7;
    {
        float p = 0.f;
        const float* w = gw + (size_t)e * H_DIM + c * 256;
        const float* xv = xs + c * 256;
        for (int j = 0; j < 256; j++) p += xv[j] * w[j];
        red[e][c] = p;
    }
    {
        float sp = 0.f;
        for (int h = tid; h < H_DIM; h += 256) sp += xs[h] * segw[h];
        sred[tid] = sp;
    }
    __syncthreads();
    for (int s = 128; s > 0; s >>= 1) {
        if (tid < s) sred[tid] += sred[tid + s];
        __syncthreads();
    }
    if (tid < 32) {
        float s = 0.f;
        for (int j = 0; j < 8; j++) s += red[tid][j];
        logit[tid] = s;
        logits_out[(size_t)t * E_NUM + tid] = s;
    }
    __syncthreads();
    if (tid == 0) {
        seg_out[t] = 1.f / (1.f + expf(-sred[0]));
        float mx = logit[0];
        for (int j = 1; j < 32; j++) mx = fmaxf(mx, logit[j]);
        float prob[32]; float sum = 0.f;
        for (int j = 0; j < 32; j++) { prob[j] = expf(logit[j] - mx); sum += prob[j]; }
        float inv = 1.f / sum;
        unsigned used = 0u;
        for (int k = 0; k < 4; k++) {
            int bi = -1; float bv = -1.f;
            for (int j = 0; j < 32; j++)
                if (!((used >> j) & 1u) && prob[j] > bv) { bv = prob[j]; bi = j; }
            used |= (1u << bi);
            topk_idx[t * 4 + k] = bi;
            topk_w[t * 4 + k] = bv * inv;
            atomicAdd(&counts[bi], 1);
        }
    }
}

// ---------------- Prefix: per-expert offsets padded to 64, tile map ----------------
__global__ __launch_bounds__(256) void prefix_kernel(
    const int* __restrict__ counts, int* __restrict__ poff,
    int* __restrict__ tile_expert, int* __restrict__ token_list,
    int* __restrict__ cursors)
{
    int tid = threadIdx.x;
    for (int i = tid; i < MAXROWS; i += 256) token_list[i] = -1;
    for (int i = tid; i < MAXT64; i += 256) tile_expert[i] = -1;
    if (tid < 32) cursors[tid] = 0;
    __syncthreads();
    if (tid == 0) {
        int off = 0;
        for (int e = 0; e < E_NUM; e++) {
            poff[e] = off;
            int pc = (counts[e] + 63) & ~63;
            for (int tl = off >> 6; tl < (off + pc) >> 6; tl++) tile_expert[tl] = e;
            off += pc;
        }
        poff[E_NUM] = off;
    }
}

// ---------------- Scatter tokens into expert segments ----------------
__global__ __launch_bounds__(256) void scatter_kernel(
    const int* __restrict__ topk_idx, const float* __restrict__ topk_w,
    const int* __restrict__ poff, int* __restrict__ cursors,
    int* __restrict__ token_list, float* __restrict__ weight_list)
{
    int p = blockIdx.x * 256 + threadIdx.x; // 0..4095
    int e = topk_idx[p];
    float w = topk_w[p];
    int pos = atomicAdd(&cursors[e], 1);
    int slot = poff[e] + pos;
    token_list[slot] = p >> 2;
    weight_list[slot] = w;
}

// =====================================================================
// 64x128 macro-tile fp32 GEMM skeleton (4x8 micro-tile per thread).
// LDS K-transposed; pads 68/132 keep staging & reads <=2-way bank alias.
// =====================================================================

// ---------------- MoE gate_up GEMM + SiLU*up fused ----------------
// per block: 64 tokens x 64 f-values (gate rows in Bs[..][0:64], up rows in [64:128])
__global__ __launch_bounds__(256) void moe_gup_kernel(
    const float* __restrict__ x, const float* __restrict__ gup,
    const int* __restrict__ tile_expert, const int* __restrict__ token_list,
    float* __restrict__ actbuf)
{
    int tile = blockIdx.y;
    int e = tile_expert[tile];
    if (e < 0) return;
    int f0 = blockIdx.x * 64;
    __shared__ __align__(16) float As[BK][68];
    __shared__ __align__(16) float Bs[BK][132];
    __shared__ int ts[64];
    int tid = threadIdx.x;
    if (tid < 64) ts[tid] = token_list[tile * 64 + tid];
    __syncthreads();
    int tx = tid & 15, ty = tid >> 4;
    int r = tid >> 2, q4 = (tid & 3) * 4;
    const float* wbase = gup + (size_t)e * (2 * F_DIM) * H_DIM;
    int tokA = ts[r];
    const float* pA  = x + (size_t)(tokA < 0 ? 0 : tokA) * H_DIM + q4;
    const float* pB0 = wbase + (size_t)(f0 + r) * H_DIM + q4;
    const float* pB1 = wbase + (size_t)(F_DIM + f0 + r) * H_DIM + q4;
    float acc[4][8];
#pragma unroll
    for (int i = 0; i < 4; i++)
#pragma unroll
        for (int j = 0; j < 8; j++) acc[i][j] = 0.f;
    float4 av = make_float4(0.f, 0.f, 0.f, 0.f), b0, b1;
    if (tokA >= 0) av = *(const float4*)pA;
    b0 = *(const float4*)pB0;
    b1 = *(const float4*)pB1;
    for (int k0 = BK; ; k0 += BK) {
        __syncthreads();
        As[q4+0][r]=av.x; As[q4+1][r]=av.y; As[q4+2][r]=av.z; As[q4+3][r]=av.w;
        Bs[q4+0][r]=b0.x; Bs[q4+1][r]=b0.y; Bs[q4+2][r]=b0.z; Bs[q4+3][r]=b0.w;
        Bs[q4+0][64+r]=b1.x; Bs[q4+1][64+r]=b1.y; Bs[q4+2][64+r]=b1.z; Bs[q4+3][64+r]=b1.w;
        __syncthreads();
        bool more = (k0 < H_DIM);
        if (more) {
            av = make_float4(0.f, 0.f, 0.f, 0.f);
            if (tokA >= 0) av = *(const float4*)(pA + k0);
            b0 = *(const float4*)(pB0 + k0);
            b1 = *(const float4*)(pB1 + k0);
        }
#pragma unroll
        for (int kk = 0; kk < BK; kk++) {
            const float4 a4 = *(const float4*)&As[kk][ty * 4];
            const float4 p4 = *(const float4*)&Bs[kk][tx * 4];
            const float4 u4 = *(const float4*)&Bs[kk][64 + tx * 4];
            float a[4] = {a4.x, a4.y, a4.z, a4.w};
            float p[4] = {p4.x, p4.y, p4.z, p4.w};
            float u[4] = {u4.x, u4.y, u4.z, u4.w};
#pragma unroll
            for (int i = 0; i < 4; i++) {
#pragma unroll
                for (int j = 0; j < 4; j++) {
                    acc[i][j]     += a[i] * p[j];
                    acc[i][4 + j] += a[i] * u[j];
                }
            }
        }
        if (!more) break;
    }
#pragma unroll
    for (int i = 0; i < 4; i++) {
        size_t row = (size_t)(tile * 64 + ty * 4 + i);
        float4 o;
        o.x = silu_mul(acc[i][0], acc[i][4]);
        o.y = silu_mul(acc[i][1], acc[i][5]);
        o.z = silu_mul(acc[i][2], acc[i][6]);
        o.w = silu_mul(acc[i][3], acc[i][7]);
        *(float4*)&actbuf[row * F_DIM + f0 + tx * 4] = o;
    }
}

// ---------------- MoE down GEMM, weighted atomicAdd into out ----------------
// per block: 64 act-rows x 128 h-values
__global__ __launch_bounds__(256) void moe_down_kernel(
    const float* __restrict__ actbuf, const float* __restrict__ dw,
    const int* __restrict__ tile_expert, const int* __restrict__ token_list,
    const float* __restrict__ weight_list, float* __restrict__ out)
{
    int tile = blockIdx.y;
    int e = tile_expert[tile];
    if (e < 0) return;
    int h0 = blockIdx.x * 128;
    __shared__ __align__(16) float As[BK][68];
    __shared__ __align__(16) float Bs[BK][132];
    __shared__ int ts[64];
    __shared__ float wl[64];
    int tid = threadIdx.x;
    if (tid < 64) {
        ts[tid] = token_list[tile * 64 + tid];
        wl[tid] = weight_list[tile * 64 + tid];
    }
    int tx = tid & 15, ty = tid >> 4;
    int r = tid >> 2, q4 = (tid & 3) * 4;
    const float* pA = actbuf + (size_t)(tile * 64 + r) * F_DIM + q4;  // padded rows are zeros
    const float* wbase = dw + (size_t)e * H_DIM * F_DIM;
    const float* pB0 = wbase + (size_t)(h0 + r) * F_DIM + q4;
    const float* pB1 = wbase + (size_t)(h0 + 64 + r) * F_DIM + q4;
    float acc[4][8];
#pragma unroll
    for (int i = 0; i < 4; i++)
#pragma unroll
        for (int j = 0; j < 8; j++) acc[i][j] = 0.f;
    float4 av = *(const float4*)pA;
    float4 b0 = *(const float4*)pB0;
    float4 b1 = *(const float4*)pB1;
    for (int k0 = BK; ; k0 += BK) {
        __syncthreads();
        As[q4+0][r]=av.x; As[q4+1][r]=av.y; As[q4+2][r]=av.z; As[q4+3][r]=av.w;
        Bs[q4+0][r]=b0.x; Bs[q4+1][r]=b0.y; Bs[q4+2][r]=b0.z; Bs[q4+3][r]=b0.w;
        Bs[q4+0][64+r]=b1.x; Bs[q4+1][64+r]=b1.y; Bs[q4+2][64+r]=b1.z; Bs[q4+3][64+r]=b1.w;
        __syncthreads();
        bool more = (k0 < F_DIM);
        if (more) {
            av = *(const float4*)(pA + k0);
            b0 = *(const float4*)(pB0 + k0);
            b1 = *(const float4*)(pB1 + k0);
        }
#pragma unroll
        for (int kk = 0; kk < BK; kk++) {
            const float4 a4 = *(const float4*)&As[kk][ty * 4];
            const float4 p4 = *(const float4*)&Bs[kk][tx * 4];
            const float4 u4 = *(const float4*)&Bs[kk][64 + tx * 4];
            float a[4] = {a4.x, a4.y, a4.z, a4.w};
            float p[4] = {p4.x, p4.y, p4.z, p4.w};
            float u[4] = {u4.x, u4.y, u4.z, u4.w};
#pragma unroll
            for (int i = 0; i < 4; i++) {
#pragma unroll
                for (int j = 0; j < 4; j++) {
                    acc[i][j]     += a[i] * p[j];
                    acc[i][4 + j] += a[i] * u[j];
                }
            }
        }
        if (!more) break;
    }
#pragma unroll
    for (int i = 0; i < 4; i++) {
        int tok = ts[ty * 4 + i];
        if (tok < 0) continue;
        float w = wl[ty * 4 + i];
        size_t base = (size_t)tok * H_DIM + h0;
#pragma unroll
        for (int j = 0; j < 4; j++) {
            atomicAdd(&out[base + tx * 4 + j], w * acc[i][j]);
            atomicAdd(&out[base + 64 + tx * 4 + j], w * acc[i][4 + j]);
        }
    }
}

// ---------------- Shared expert gate/up + SiLU*up ----------------
__global__ __launch_bounds__(256) void shared_gup_kernel(
    const float* __restrict__ x, const float* __restrict__ wg,
    const float* __restrict__ wu, float* __restrict__ sact)
{
    int tile = blockIdx.y;          // 16 token tiles of 64
    int f0 = blockIdx.x * 64;       // 88 f tiles
    __shared__ __align__(16) float As[BK][68];
    __shared__ __align__(16) float Bs[BK][132];
    int tid = threadIdx.x;
    int tx = tid & 15, ty = tid >> 4;
    int r = tid >> 2, q4 = (tid & 3) * 4;
    const float* pA  = x + (size_t)(tile * 64 + r) * H_DIM + q4;
    const float* pB0 = wg + (size_t)(f0 + r) * H_DIM + q4;
    const float* pB1 = wu + (size_t)(f0 + r) * H_DIM + q4;
    float acc[4][8];
#pragma unroll
    for (int i = 0; i < 4; i++)
#pragma unroll
        for (int j = 0; j < 8; j++) acc[i][j] = 0.f;
    float4 av = *(const float4*)pA;
    float4 b0 = *(const float4*)pB0;
    float4 b1 = *(const float4*)pB1;
    for (int k0 = BK; ; k0 += BK) {
        __syncthreads();
        As[q4+0][r]=av.x; As[q4+1][r]=av.y; As[q4+2][r]=av.z; As[q4+3][r]=av.w;
        Bs[q4+0][r]=b0.x; Bs[q4+1][r]=b0.y; Bs[q4+2][r]=b0.z; Bs[q4+3][r]=b0.w;
        Bs[q4+0][64+r]=b1.x; Bs[q4+1][64+r]=b1.y; Bs[q4+2][64+r]=b1.z; Bs[q4+3][64+r]=b1.w;
        __syncthreads();
        bool more = (k0 < H_DIM);
        if (more) {
            av = *(const float4*)(pA + k0);
            b0 = *(const float4*)(pB0 + k0);
            b1 = *(const float4*)(pB1 + k0);
        }
#pragma unroll
        for (int kk = 0; kk < BK; kk++) {
            const float4 a4 = *(const float4*)&As[kk][ty * 4];
            const float4 p4 = *(const float4*)&Bs[kk][tx * 4];
            const float4 u4 = *(const float4*)&Bs[kk][64 + tx * 4];
            float a[4] = {a4.x, a4.y, a4.z, a4.w};
            float p[4] = {p4.x, p4.y, p4.z, p4.w};
            float u[4] = {u4.x, u4.y, u4.z, u4.w};
#pragma unroll
            for (int i = 0; i < 4; i++) {
#pragma unroll
                for (int j = 0; j < 4; j++) {
                    acc[i][j]     += a[i] * p[j];
                    acc[i][4 + j] += a[i] * u[j];
                }
            }
        }
        if (!more) break;
    }
#pragma unroll
    for (int i = 0; i < 4; i++) {
        size_t row = (size_t)(tile * 64 + ty * 4 + i);
        float4 o;
        o.x = silu_mul(acc[i][0], acc[i][4]);
        o.y = silu_mul(acc[i][1], acc[i][5]);
        o.z = silu_mul(acc[i][2], acc[i][6]);
        o.w = silu_mul(acc[i][3], acc[i][7]);
        *(float4*)&sact[row * SF_DIM + f0 + tx * 4] = o;
    }
}

// ---------------- Shared expert down, sigmoid-gated plain RMW into out ----------------
// (runs after moe_down in-stream; each out element touched by exactly one thread)
__global__ __launch_bounds__(256) void shared_down_kernel(
    const float* __restrict__ sact, const float* __restrict__ sdw,
    const float* __restrict__ seg, float* __restrict__ out)
{
    int tile = blockIdx.y;
    int h0 = blockIdx.x * 128;
    __shared__ __align__(16) float As[BK][68];
    __shared__ __align__(16) float Bs[BK][132];
    int tid = threadIdx.x;
    int tx = tid & 15, ty = tid >> 4;
    int r = tid >> 2, q4 = (tid & 3) * 4;
    const float* pA  = sact + (size_t)(tile * 64 + r) * SF_DIM + q4;
    const float* pB0 = sdw + (size_t)(h0 + r) * SF_DIM + q4;
    const float* pB1 = sdw + (size_t)(h0 + 64 + r) * SF_DIM + q4;
    float acc[4][8];
#pragma unroll
    for (int i = 0; i < 4; i++)
#pragma unroll
        for (int j = 0; j < 8; j++) acc[i][j] = 0.f;
    float4 av = *(const float4*)pA;
    float4 b0 = *(const float4*)pB0;
    float4 b1 = *(const float4*)pB1;
    for (int k0 = BK; ; k0 += BK) {
        __syncthreads();
        As[q4+0][r]=av.x; As[q4+1][r]=av.y; As[q4+2][r]=av.z; As[q4+3][r]=av.w;
        Bs[q4+0][r]=b0.x; Bs[q4+1][r]=b0.y; Bs[q4+2][r]=b0.z; Bs[q4+3][r]=b0.w;
        Bs[q4+0][64+r]=b1.x; Bs[q4+1][64+r]=b1.y; Bs[q4+2][64+r]=b1.z; Bs[q4+3][64+r]=b1.w;
        __syncthreads();
        bool more = (k0 < SF_DIM);
        if (more) {
            av = *(const float4*)(pA + k0);
            b0 = *(const float4*)(pB0 + k0);
            b1 = *(const float4*)(pB1 + k0);
        }
#pragma unroll
        for (int kk = 0; kk < BK; kk++) {
            const float4 a4 = *(const float4*)&As[kk][ty * 4];
            const float4 p4 = *(const float4*)&Bs[kk][tx * 4];
            const float4 u4 = *(const float4*)&Bs[kk][64 + tx * 4];
            float a[4] = {a4.x, a4.y, a4.z, a4.w};
            float p[4] = {p4.x, p4.y, p4.z, p4.w};
            float u[4] = {u4.x, u4.y, u4.z, u4.w};
#pragma unroll
            for (int i = 0; i < 4; i++) {
#pragma unroll
                for (int j = 0; j < 4; j++) {
                    acc[i][j]     += a[i] * p[j];
                    acc[i][4 + j] += a[i] * u[j];
                }
            }
        }
        if (!more) break;
    }
#pragma unroll
    for (int i = 0; i < 4; i++) {
        int tok = tile * 64 + ty * 4 + i;
        float sc = seg[tok];
        size_t base = (size_t)tok * H_DIM + h0;
        float4 o0 = *(float4*)&out[base + tx * 4];
        o0.x += sc * acc[i][0]; o0.y += sc * acc[i][1];
        o0.z += sc * acc[i][2]; o0.w += sc * acc[i][3];
        *(float4*)&out[base + tx * 4] = o0;
        float4 o1 = *(float4*)&out[base + 64 + tx * 4];
        o1.x += sc * acc[i][4]; o1.y += sc * acc[i][5];
        o1.z += sc * acc[i][6]; o1.w += sc * acc[i][7];
        *(float4*)&out[base + 64 + tx * 4] = o1;
    }
}

extern "C" void kernel_launch(void* const* d_in, const int* in_sizes, int n_in,
                              void* d_out, int out_size, void* d_ws, size_t ws_size,
                              hipStream_t stream) {
    const float* x    = (const float*)d_in[0];
    const float* gw   = (const float*)d_in[1];
    const float* gup  = (const float*)d_in[2];
    const float* dw   = (const float*)d_in[3];
    const float* sgw  = (const float*)d_in[4];
    const float* suw  = (const float*)d_in[5];
    const float* sdw  = (const float*)d_in[6];
    const float* segw = (const float*)d_in[7];
    float* out        = (float*)d_out;               // 1024*2048
    float* logits_out = out + (size_t)T_TOK * H_DIM; // 1024*32

    // workspace layout (floats)
    float* wsf = (float*)d_ws;
    int*   topk_idx    = (int*)wsf;                       // 4096
    float* topk_w      = wsf + 4096;                      // 4096
    int*   counts      = (int*)(wsf + 8192);              // 32
    int*   poff        = counts + 32;                     // 33
    int*   cursors     = poff + 33;                       // 32
    int*   tile_expert = cursors + 32;                    // 96
    int*   token_list  = tile_expert + 96;                // 6144
    float* weight_list = (float*)(token_list + 6144);     // 6144
    float* seg         = weight_list + 6144;              // 1024  (ends at 21697)
    float* actbuf      = wsf + 21760;                     // max(6144*1408, 1024*5632) floats

    hipMemsetAsync(d_out, 0, (size_t)out_size * sizeof(float), stream);
    hipMemsetAsync(counts, 0, 32 * sizeof(int), stream);

    router_kernel<<<T_TOK, 256, 0, stream>>>(x, gw, segw, logits_out, topk_idx, topk_w, seg, counts);
    prefix_kernel<<<1, 256, 0, stream>>>(counts, poff, tile_expert, token_list, cursors);
    scatter_kernel<<<PAIRS / 256, 256, 0, stream>>>(topk_idx, topk_w, poff, cursors, token_list, weight_list);

    moe_gup_kernel<<<dim3(F_DIM / 64, MAXT64), 256, 0, stream>>>(x, gup, tile_expert, token_list, actbuf);
    moe_down_kernel<<<dim3(H_DIM / 128, MAXT64), 256, 0, stream>>>(actbuf, dw, tile_expert, token_list, weight_list, out);

    shared_gup_kernel<<<dim3(SF_DIM / 64, T_TOK / 64), 256, 0, stream>>>(x, sgw, suw, actbuf);
    shared_down_kernel<<<dim3(H_DIM / 128, T_TOK / 64), 256, 0, stream>>>(actbuf, sdw, seg, out);
}